// Round 6
// baseline (3475.327 us; speedup 1.0000x reference)
//
#include <hip/hip_runtime.h>

typedef unsigned int u32;
typedef unsigned long long u64;

// coordinates (B=8, N=8192, 3) f32, features (B=8, N=8192, C=128) f32
// out: coords (B, M=2048, 3) ++ features (B, M, C=128), flat f32
#define BB 8
#define NN 8192
#define MM 2048
#define KK 32
#define CC 128

#define FPS_T 512           // threads per FPS workgroup (8 waves)
#define FPS_P (NN / FPS_T)  // 16 points per thread

// ---------------------------------------------------------------------------
// DPP helpers (proven in round 5): full-wave reduce, result valid in lane 63.
// ---------------------------------------------------------------------------
template <int Ctrl, int RowMask>
__device__ __forceinline__ int dpp_i(int x) {
  return __builtin_amdgcn_update_dpp(x, x, Ctrl, RowMask, 0xf, false);
}

template <int Ctrl, int RowMask>
__device__ __forceinline__ double dpp_d(double v) {
  const u64 b = (u64)__double_as_longlong(v);
  const int lo = dpp_i<Ctrl, RowMask>((int)(u32)b);
  const int hi = dpp_i<Ctrl, RowMask>((int)(u32)(b >> 32));
  return __longlong_as_double((long long)(((u64)(u32)hi << 32) | (u32)lo));
}

__device__ __forceinline__ u32 wave_minu63(u32 v) {
  u32 o;
  o = (u32)dpp_i<0x111, 0xf>((int)v); v = o < v ? o : v;  // shr1
  o = (u32)dpp_i<0x112, 0xf>((int)v); v = o < v ? o : v;  // shr2
  o = (u32)dpp_i<0x114, 0xf>((int)v); v = o < v ? o : v;  // shr4
  o = (u32)dpp_i<0x118, 0xf>((int)v); v = o < v ? o : v;  // shr8
  o = (u32)dpp_i<0x142, 0xa>((int)v); v = o < v ? o : v;  // bcast15
  o = (u32)dpp_i<0x143, 0xc>((int)v); v = o < v ? o : v;  // bcast31
  return v;  // lane 63 holds wave min
}

__device__ __forceinline__ double wave_minf64_63(double v) {
  v = fmin(v, dpp_d<0x111, 0xf>(v));
  v = fmin(v, dpp_d<0x112, 0xf>(v));
  v = fmin(v, dpp_d<0x114, 0xf>(v));
  v = fmin(v, dpp_d<0x118, 0xf>(v));
  v = fmin(v, dpp_d<0x142, 0xa>(v));
  v = fmin(v, dpp_d<0x143, 0xc>(v));
  return v;  // lane 63 holds wave min (all values positive f64, no NaN)
}

// d2-part of an FPS packed value: bits = (f32bits(d2) << 31) | (8191 - idx)
__device__ __forceinline__ float pk_d2(double p) {
  return __uint_as_float((u32)(((u64)__double_as_longlong(p)) >> 31));
}

// ---------------------------------------------------------------------------
// FPS, squared-distance space, exact, ONE cross-wave round trip per iteration.
// Wave top-2 reduce: m1 = packed (d2bits<<31 | 8191-idx) argmax via v_max_f64
// (positive-f64 bit pattern == u64 order); m2 = plain f32 second-max value.
// After one barrier: gmax, candidate widx, runner-up g2. lo_f = smallest
// float whose sqrt_rn equals sqrt_rn(gmax) (verbatim round-4/5 math).
// Fast path (g2 < lo_f): no point lies in [lo_f, gmax) -> candidate is
// EXACTLY the reference argmax winner. Rare path: verbatim round-5 scan +
// u32 reduce (second barrier; decision is block-uniform -> barrier-safe).
// ---------------------------------------------------------------------------
__global__ __launch_bounds__(FPS_T, 1)
void fps_kernel(const float* __restrict__ coords, float* __restrict__ out_coords) {
  const int b = blockIdx.x;
  const int t = threadIdx.x;
  const float* cb = coords + (size_t)b * NN * 3;

  __shared__ float s_x[NN], s_y[NN], s_z[NN];  // 96 KB coords mirror
  __shared__ double s_m1[2][FPS_T / 64];       // parity-buffered partials
  __shared__ float s_m2[2][FPS_T / 64];
  __shared__ u32 s_ri[2][FPS_T / 64];          // rare-path partials

  float x[FPS_P], y[FPS_P], z[FPS_P], d2m[FPS_P];
#pragma unroll
  for (int j = 0; j < FPS_P; ++j) {
    const int p = t + j * FPS_T;
    x[j] = cb[p * 3 + 0];
    y[j] = cb[p * 3 + 1];
    z[j] = cb[p * 3 + 2];
    d2m[j] = 1e20f;  // sqrt-space 1e10 == d2-space 1e20
    s_x[p] = x[j]; s_y[p] = y[j]; s_z[p] = z[j];
  }
  // staging writes ordered before first s_x read by iteration-1 barrier

  if (t == 0) {
    out_coords[(size_t)(b * MM) * 3 + 0] = cb[0];
    out_coords[(size_t)(b * MM) * 3 + 1] = cb[1];
    out_coords[(size_t)(b * MM) * 3 + 2] = cb[2];
  }
  float cx = cb[0], cy = cb[1], cz = cb[2];

  for (int it = 1; it < MM; ++it) {
    const int par = it & 1;

    // --- update squared dists; thread-local top-2 (verbatim d2 math) ---
    float tm1 = -1.0f, tm2 = -1.0f;
#pragma unroll
    for (int j = 0; j < FPS_P; ++j) {
      const float dx = __fsub_rn(x[j], cx);
      const float dy = __fsub_rn(y[j], cy);
      const float dz = __fsub_rn(z[j], cz);
      const float d2 = __fadd_rn(__fadd_rn(__fmul_rn(dx, dx), __fmul_rn(dy, dy)),
                                 __fmul_rn(dz, dz));
      const float nd = fminf(d2m[j], d2);
      d2m[j] = nd;
      const float lo = fminf(tm1, nd);
      tm1 = fmaxf(tm1, nd);
      tm2 = fmaxf(tm2, lo);
    }

    // --- locate thread-min index at tm1; pack (d2bits<<31 | 8191-idx) ---
    u32 mi = 0xFFFFFFFFu;
#pragma unroll
    for (int j = 0; j < FPS_P; ++j) {
      const u32 pi = (u32)(t + j * FPS_T);
      if (d2m[j] == tm1 && pi < mi) mi = pi;
    }
    double m1 = __longlong_as_double(
        (long long)(((u64)__float_as_uint(tm1) << 31) | (u64)(8191u - mi)));
    float m2 = tm2;

    // --- wave top-2 reduce (m1 packed f64 max, m2 f32 value-only) ---
#define FPS_T2_STEP(CTRL, MASK)                                              \
  {                                                                          \
    const double o1 = dpp_d<CTRL, MASK>(m1);                                 \
    const float o2 = __int_as_float(dpp_i<CTRL, MASK>(__float_as_int(m2)));  \
    const double lo2 = fmin(m1, o1);                                         \
    m1 = fmax(m1, o1);                                                       \
    m2 = fmaxf(fmaxf(m2, o2), pk_d2(lo2));                                   \
  }
    FPS_T2_STEP(0x111, 0xf)
    FPS_T2_STEP(0x112, 0xf)
    FPS_T2_STEP(0x114, 0xf)
    FPS_T2_STEP(0x118, 0xf)
    FPS_T2_STEP(0x142, 0xa)
    FPS_T2_STEP(0x143, 0xc)
#undef FPS_T2_STEP

    if ((t & 63) == 63) {
      s_m1[par][t >> 6] = m1;
      s_m2[par][t >> 6] = m2;
    }
    __syncthreads();  // the ONE barrier (parity buffers prevent races)

    // --- combine partials (uniform across all waves) ---
    double g1 = s_m1[par][0];
#pragma unroll
    for (int w = 1; w < FPS_T / 64; ++w) g1 = fmax(g1, s_m1[par][w]);
    float g2 = -1.0f;
#pragma unroll
    for (int w = 0; w < FPS_T / 64; ++w) {
      const double pw = s_m1[par][w];
      const float contrib = (pw == g1) ? s_m2[par][w] : pk_d2(pw);
      g2 = fmaxf(g2, contrib);
    }
    const u64 g1b = (u64)__double_as_longlong(g1);
    const float gmax = __uint_as_float((u32)(g1b >> 31));
    const u32 cand = 8191u - (u32)(g1b & 0x1FFFull);

    // --- exact sqrt-space tie threshold (verbatim round-4/5) ---
    float lo_f;
    if (!(gmax > 0.0f)) {
      lo_f = 0.0f;
    } else {
      const float s = __fsqrt_rn(gmax);                        // == ref max dist
      const float sp = __int_as_float(__float_as_int(s) - 1);  // nextafter down
      const double mid = 0.5 * ((double)s + (double)sp);       // exact
      const double lod = mid * mid;                            // exact
      float c = (float)lod;
      if ((double)c < lod) c = __int_as_float(__float_as_int(c) + 1);  // ceil
      lo_f = c;  // d2 >= lo_f  <=>  sqrt_rn(d2) == s   (for d2 <= gmax)
    }

    u32 widx;
    if (g2 < lo_f) {
      widx = cand;  // fast path: provably no interloper in [lo_f, gmax)
    } else {
      // rare path (block-uniform): verbatim round-5 scan + u32 reduce
      u32 ri = 0xFFFFFFFFu;
      if (tm1 >= lo_f) {
#pragma unroll
        for (int j = 0; j < FPS_P; ++j) {
          const u32 pi = (u32)(t + j * FPS_T);
          if (d2m[j] >= lo_f && pi < ri) ri = pi;
        }
      }
      const u32 wi = wave_minu63(ri);
      if ((t & 63) == 63) s_ri[par][t >> 6] = wi;
      __syncthreads();
      widx = s_ri[par][0];
#pragma unroll
      for (int w = 1; w < FPS_T / 64; ++w)
        widx = s_ri[par][w] < widx ? s_ri[par][w] : widx;
    }

    // --- centroid broadcast: uniform-address LDS read ---
    cx = s_x[widx]; cy = s_y[widx]; cz = s_z[widx];
    if (t == 0) {  // off-critical-path output write
      float* oc = out_coords + ((size_t)b * MM + it) * 3;
      oc[0] = cx; oc[1] = cy; oc[2] = cz;
    }
  }
}

// ---------------------------------------------------------------------------
// KNN top-32 + feature mean. Key = (flipped-d2-bits << 31) | idx, always a
// positive finite f64 bit pattern -> v_min_f64 is exact (d2, idx) lexicographic
// min == lax.top_k stable order. Winners arrive in increasing key order, so
// the owner repairs with min{key > g} -- keys are never modified (no scratch,
// no writeback). Thread-contiguous mapping p = t*32+j gives float4 loads.
// ---------------------------------------------------------------------------
__global__ __launch_bounds__(256, 4)
void knn_mean_kernel(const float* __restrict__ coords,
                     const float* __restrict__ feats,
                     const float* __restrict__ out_coords,
                     float* __restrict__ out_feats) {
  const int q = blockIdx.x;   // b*MM + m
  const int b = q >> 11;
  const int t = threadIdx.x;
  const float* cb = coords + (size_t)b * NN * 3;

  const float cx = out_coords[(size_t)q * 3 + 0];
  const float cy = out_coords[(size_t)q * 3 + 1];
  const float cz = out_coords[(size_t)q * 3 + 2];
  const float c2 = __fadd_rn(__fadd_rn(__fmul_rn(cx, cx), __fmul_rn(cy, cy)),
                             __fmul_rn(cz, cz));

  const double HUGE_SENT = __longlong_as_double(0x7FE0000000000000LL);
  double key[32];
  double lmin = HUGE_SENT;
  const float* tb = cb + t * 96;  // 32 points * 3 floats, 16B-aligned

#pragma unroll
  for (int ch = 0; ch < 8; ++ch) {  // 4 points per chunk, 3 float4 loads
    const float4 q0 = *(const float4*)(tb + ch * 12 + 0);
    const float4 q1 = *(const float4*)(tb + ch * 12 + 4);
    const float4 q2 = *(const float4*)(tb + ch * 12 + 8);
    const float pxs[4] = {q0.x, q0.w, q1.z, q2.y};
    const float pys[4] = {q0.y, q1.x, q1.w, q2.z};
    const float pzs[4] = {q0.z, q1.y, q2.x, q2.w};
#pragma unroll
    for (int k = 0; k < 4; ++k) {
      const int j = ch * 4 + k;
      const int p = t * 32 + j;
      const float px = pxs[k], py = pys[k], pz = pzs[k];
      const float p2 = __fadd_rn(__fadd_rn(__fmul_rn(px, px), __fmul_rn(py, py)),
                                 __fmul_rn(pz, pz));
      const float dot = __fmaf_rn(cz, pz, __fmaf_rn(cy, py, __fmul_rn(cx, px)));
      const float d2 = __fsub_rn(__fadd_rn(c2, p2), __fadd_rn(dot, dot));
      u32 ub = __float_as_uint(d2);                  // order-preserving flip
      ub ^= (((u32)((int)ub >> 31)) | 0x80000000u);
      key[j] = __longlong_as_double(
          (long long)(((u64)ub << 31) | (u32)p));    // positive f64, no NaN
      lmin = fmin(lmin, key[j]);
    }
  }

  __shared__ double s_pmin[2][4];  // parity-buffered wave partials
  __shared__ int s_nbr[KK];

  for (int r = 0; r < KK; ++r) {
    const double wv = wave_minf64_63(lmin);
    if ((t & 63) == 63) s_pmin[r & 1][t >> 6] = wv;
    __syncthreads();  // one barrier per round

    const double* pm = s_pmin[r & 1];
    const double g = fmin(fmin(pm[0], pm[1]), fmin(pm[2], pm[3]));
    const int widx = (int)((u64)__double_as_longlong(g) & 0x1FFFull);

    if (t == (widx >> 5)) {  // owner: repair lmin = min{key > g}; keys const
      double nm = HUGE_SENT;
#pragma unroll
      for (int j = 0; j < 32; ++j) {
        const double sel = (key[j] > g) ? key[j] : HUGE_SENT;
        nm = fmin(nm, sel);
      }
      lmin = nm;
    }
    if (t == 0) s_nbr[r] = widx;
  }
  __syncthreads();  // s_nbr complete

  // --- feature mean: thread t -> channel t&127, half t>>7 sums 16 rows ---
  const int c = t & (CC - 1);
  const int half = t >> 7;
  const float* fb = feats + (size_t)b * NN * CC;
  float s = 0.0f;
#pragma unroll
  for (int k = 0; k < 16; ++k) {
    const int p = s_nbr[half * 16 + k];
    s = __fadd_rn(s, fb[(size_t)p * CC + c]);
  }
  __shared__ float s_sum[CC];
  if (half == 1) s_sum[c] = s;
  __syncthreads();
  if (half == 0) {
    const float tot = __fadd_rn(s, s_sum[c]);        // (k0..15)+(k16..31)
    out_feats[(size_t)q * CC + c] = tot * 0.03125f;  // exact /32
  }
}

// ---------------------------------------------------------------------------
extern "C" void kernel_launch(void* const* d_in, const int* in_sizes, int n_in,
                              void* d_out, int out_size, void* d_ws, size_t ws_size,
                              hipStream_t stream) {
  const float* coords = (const float*)d_in[0];
  const float* feats  = (const float*)d_in[1];
  float* out_coords = (float*)d_out;                        // B*M*3
  float* out_feats  = (float*)d_out + (size_t)BB * MM * 3;  // B*M*C

  fps_kernel<<<BB, FPS_T, 0, stream>>>(coords, out_coords);
  knn_mean_kernel<<<BB * MM, 256, 0, stream>>>(coords, feats, out_coords,
                                               out_feats);
}

// Round 7
// 2498.852 us; speedup vs baseline: 1.3908x; 1.3908x over previous
//
#include <hip/hip_runtime.h>

typedef unsigned int u32;
typedef unsigned long long u64;
typedef float f32x2 __attribute__((ext_vector_type(2)));

// coordinates (B=8, N=8192, 3) f32, features (B=8, N=8192, C=128) f32
// out: coords (B, M=2048, 3) ++ features (B, M, C=128), flat f32
#define BB 8
#define NN 8192
#define MM 2048
#define KK 32
#define CC 128

#define FPS_T 512        // threads per FPS workgroup (8 waves)
#define FPS_PAIRS 8      // f32x2 pairs per thread (16 points)

// ---------------------------------------------------------------------------
// DPP helpers (HW-proven round 5): full-wave reduce valid in lane 63; plus
// the canonical GCN inclusive prefix-scan (add) for the radix histogram.
// ---------------------------------------------------------------------------
template <int Ctrl, int RowMask>
__device__ __forceinline__ int dpp_mov(int x) {
  return __builtin_amdgcn_update_dpp(x, x, Ctrl, RowMask, 0xf, false);
}
template <int Ctrl, int RowMask>
__device__ __forceinline__ u32 dpp_scan_add(u32 x) {
  return x + (u32)__builtin_amdgcn_update_dpp(0, (int)x, Ctrl, RowMask, 0xf, false);
}

__device__ __forceinline__ float wave_max63(float v) {
  v = fmaxf(v, __int_as_float(dpp_mov<0x111, 0xf>(__float_as_int(v))));  // shr1
  v = fmaxf(v, __int_as_float(dpp_mov<0x112, 0xf>(__float_as_int(v))));  // shr2
  v = fmaxf(v, __int_as_float(dpp_mov<0x114, 0xf>(__float_as_int(v))));  // shr4
  v = fmaxf(v, __int_as_float(dpp_mov<0x118, 0xf>(__float_as_int(v))));  // shr8
  v = fmaxf(v, __int_as_float(dpp_mov<0x142, 0xa>(__float_as_int(v))));  // bc15
  v = fmaxf(v, __int_as_float(dpp_mov<0x143, 0xc>(__float_as_int(v))));  // bc31
  return v;
}

__device__ __forceinline__ u32 wave_minu63(u32 v) {
  u32 o;
  o = (u32)dpp_mov<0x111, 0xf>((int)v); v = o < v ? o : v;
  o = (u32)dpp_mov<0x112, 0xf>((int)v); v = o < v ? o : v;
  o = (u32)dpp_mov<0x114, 0xf>((int)v); v = o < v ? o : v;
  o = (u32)dpp_mov<0x118, 0xf>((int)v); v = o < v ? o : v;
  o = (u32)dpp_mov<0x142, 0xa>((int)v); v = o < v ? o : v;
  o = (u32)dpp_mov<0x143, 0xc>((int)v); v = o < v ? o : v;
  return v;
}

__device__ __forceinline__ u32 wave_scan_incl(u32 x) {
  x = dpp_scan_add<0x111, 0xf>(x);
  x = dpp_scan_add<0x112, 0xf>(x);
  x = dpp_scan_add<0x114, 0xf>(x);
  x = dpp_scan_add<0x118, 0xf>(x);
  x = dpp_scan_add<0x142, 0xa>(x);
  x = dpp_scan_add<0x143, 0xc>(x);
  return x;  // inclusive prefix sum across 64 lanes
}

// packed-f32 ops (element-wise IEEE rn, identical to scalar __fadd/__fmul_rn)
#define PK_ADD(d, a, b) asm("v_pk_add_f32 %0, %1, %2" : "=v"(d) : "v"(a), "v"(b))
#define PK_MUL(d, a, b) asm("v_pk_mul_f32 %0, %1, %2" : "=v"(d) : "v"(a), "v"(b))

// ---------------------------------------------------------------------------
// FPS: round-5 structure (best measured) with pk-f32 update loop.
// d2-space argmax + exact sqrt-space tie repair; 2 barriers/iter, 0 atomics;
// centroid broadcast via uniform-address LDS read.
// ---------------------------------------------------------------------------
__global__ __launch_bounds__(FPS_T, 1)
void fps_kernel(const float* __restrict__ coords, float* __restrict__ out_coords) {
  const int b = blockIdx.x;
  const int t = threadIdx.x;
  const float* cb = coords + (size_t)b * NN * 3;

  __shared__ float s_x[NN], s_y[NN], s_z[NN];  // 96 KB coords mirror
  __shared__ float s_gpart[FPS_T / 64];
  __shared__ u32 s_ipart[FPS_T / 64];

  f32x2 x[FPS_PAIRS], y[FPS_PAIRS], z[FPS_PAIRS], d2m[FPS_PAIRS];
#pragma unroll
  for (int k = 0; k < FPS_PAIRS; ++k) {
    const int p0 = t + (2 * k) * FPS_T;
    const int p1 = t + (2 * k + 1) * FPS_T;
    x[k].x = cb[p0 * 3 + 0]; x[k].y = cb[p1 * 3 + 0];
    y[k].x = cb[p0 * 3 + 1]; y[k].y = cb[p1 * 3 + 1];
    z[k].x = cb[p0 * 3 + 2]; z[k].y = cb[p1 * 3 + 2];
    d2m[k].x = 1e20f; d2m[k].y = 1e20f;  // sqrt-space 1e10 == d2-space 1e20
    s_x[p0] = x[k].x; s_x[p1] = x[k].y;
    s_y[p0] = y[k].x; s_y[p1] = y[k].y;
    s_z[p0] = z[k].x; s_z[p1] = z[k].y;
  }
  // staging writes ordered before first s_x[widx] read by barrier A below

  if (t == 0) {
    out_coords[(size_t)(b * MM) * 3 + 0] = cb[0];
    out_coords[(size_t)(b * MM) * 3 + 1] = cb[1];
    out_coords[(size_t)(b * MM) * 3 + 2] = cb[2];
  }
  float cx = cb[0], cy = cb[1], cz = cb[2];

  for (int it = 1; it < MM; ++it) {
    // --- update squared dists (pk math, exact); thread-local max ---
    const f32x2 ncx = {-cx, -cx}, ncy = {-cy, -cy}, ncz = {-cz, -cz};
    f32x2 bv = {-1.0f, -1.0f};
#pragma unroll
    for (int k = 0; k < FPS_PAIRS; ++k) {
      f32x2 dx, dy, dz, t0, t1, t2, d2;
      PK_ADD(dx, x[k], ncx);           // x - cx (exact: rn(x + (-cx)))
      PK_ADD(dy, y[k], ncy);
      PK_ADD(dz, z[k], ncz);
      PK_MUL(t0, dx, dx);
      PK_MUL(t1, dy, dy);
      PK_ADD(t0, t0, t1);              // dx*dx + dy*dy
      PK_MUL(t2, dz, dz);
      PK_ADD(d2, t0, t2);              // (dx*dx + dy*dy) + dz*dz
      d2m[k].x = fminf(d2m[k].x, d2.x);
      d2m[k].y = fminf(d2m[k].y, d2.y);
      bv.x = fmaxf(bv.x, d2m[k].x);
      bv.y = fmaxf(bv.y, d2m[k].y);
    }
    const float bestv = fmaxf(bv.x, bv.y);

    // --- phase 1: global max via DPP + one LDS/barrier hop ---
    const float wv = wave_max63(bestv);
    if ((t & 63) == 63) s_gpart[t >> 6] = wv;
    __syncthreads();  // A
    float gmax = s_gpart[0];
#pragma unroll
    for (int w = 1; w < FPS_T / 64; ++w) gmax = fmaxf(gmax, s_gpart[w]);

    // --- exact sqrt-space tie threshold (verbatim rounds 4-6) ---
    float lo_f;
    if (!(gmax > 0.0f)) {
      lo_f = 0.0f;
    } else {
      const float s = __fsqrt_rn(gmax);                        // == ref max dist
      const float sp = __int_as_float(__float_as_int(s) - 1);  // nextafter down
      const double mid = 0.5 * ((double)s + (double)sp);       // exact
      const double lod = mid * mid;                            // exact
      float c = (float)lod;
      if ((double)c < lod) c = __int_as_float(__float_as_int(c) + 1);  // ceil
      lo_f = c;  // d2 >= lo_f  <=>  sqrt_rn(d2) == s   (for d2 <= gmax)
    }

    // --- phase 2: min index among d2m >= lo_f (execz-skipped for most) ---
    u32 mi = 0xFFFFFFFFu;
    if (bestv >= lo_f) {
#pragma unroll
      for (int k = 0; k < FPS_PAIRS; ++k) {
        const u32 p0 = (u32)(t + (2 * k) * FPS_T);
        const u32 p1 = (u32)(t + (2 * k + 1) * FPS_T);
        if (d2m[k].x >= lo_f && p0 < mi) mi = p0;
        if (d2m[k].y >= lo_f && p1 < mi) mi = p1;
      }
    }
    const u32 wi = wave_minu63(mi);
    if ((t & 63) == 63) s_ipart[t >> 6] = wi;
    __syncthreads();  // B
    u32 widx = s_ipart[0];
#pragma unroll
    for (int w = 1; w < FPS_T / 64; ++w)
      widx = s_ipart[w] < widx ? s_ipart[w] : widx;

    // --- centroid broadcast: uniform-address LDS read ---
    cx = s_x[widx]; cy = s_y[widx]; cz = s_z[widx];
    if (t == (it & (FPS_T - 1))) {  // off-critical-path output store
      float* oc = out_coords + ((size_t)b * MM + it) * 3;
      oc[0] = cx; oc[1] = cy; oc[2] = cz;
    }
  }
}

// ---------------------------------------------------------------------------
// KNN top-32 + feature mean via EXACT radix-select (mean is order-invariant;
// only the set of 32 smallest 45-bit keys (flipped-d2<<13 | idx) matters —
// identical to lax.top_k's (d2, idx) lexicographic set).
// Digit plan: 12,11,11,11 bits (shifts 33,22,11,0); 4096-bin LDS histogram;
// DPP prefix-scan; uniform early break (typically 2 passes); extraction is
// key <= THR with THR = exact 32nd-smallest boundary (exactly 32 winners).
// ---------------------------------------------------------------------------
__global__ __launch_bounds__(256, 4)
void knn_mean_kernel(const float* __restrict__ coords,
                     const float* __restrict__ feats,
                     const float* __restrict__ out_coords,
                     float* __restrict__ out_feats) {
  const int q = blockIdx.x;   // b*MM + m
  const int b = q >> 11;
  const int t = threadIdx.x;
  const float* cb = coords + (size_t)b * NN * 3;

  const float cx = out_coords[(size_t)q * 3 + 0];
  const float cy = out_coords[(size_t)q * 3 + 1];
  const float cz = out_coords[(size_t)q * 3 + 2];
  const float c2 = __fadd_rn(__fadd_rn(__fmul_rn(cx, cx), __fmul_rn(cy, cy)),
                             __fmul_rn(cz, cz));

  // --- flipped-d2 keys, thread-contiguous float4 loads (round-6 proven) ---
  u32 D[32];
  const float* tb = cb + t * 96;  // 32 points * 3 floats
#pragma unroll
  for (int ch = 0; ch < 8; ++ch) {
    const float4 q0 = *(const float4*)(tb + ch * 12 + 0);
    const float4 q1 = *(const float4*)(tb + ch * 12 + 4);
    const float4 q2 = *(const float4*)(tb + ch * 12 + 8);
    const float pxs[4] = {q0.x, q0.w, q1.z, q2.y};
    const float pys[4] = {q0.y, q1.x, q1.w, q2.z};
    const float pzs[4] = {q0.z, q1.y, q2.x, q2.w};
#pragma unroll
    for (int kk = 0; kk < 4; ++kk) {
      const int j = ch * 4 + kk;
      const float px = pxs[kk], py = pys[kk], pz = pzs[kk];
      const float p2 = __fadd_rn(__fadd_rn(__fmul_rn(px, px), __fmul_rn(py, py)),
                                 __fmul_rn(pz, pz));
      const float dot = __fmaf_rn(cz, pz, __fmaf_rn(cy, py, __fmul_rn(cx, px)));
      const float d2 = __fsub_rn(__fadd_rn(c2, p2), __fadd_rn(dot, dot));
      u32 ub = __float_as_uint(d2);                 // order-preserving flip
      ub ^= (((u32)((int)ub >> 31)) | 0x80000000u);
      D[j] = ub;
    }
  }

  __shared__ u32 s_hist[4096];
  __shared__ u32 s_wsum[4];
  __shared__ u32 s_bin, s_r, s_full;
  __shared__ u32 s_cnt;
  __shared__ int s_nbr[KK];
  __shared__ float s_sum[CC];

  const int w = t >> 6;
  u64 hi = 0;        // resolved high digits of the 45-bit key
  u32 k_rem = KK;    // remaining count to take within current candidate set
  u64 thr = 0;       // final: exactly 32 keys are <= thr
  bool done = false; // block-uniform

  constexpr int SHIFT[4] = {33, 22, 11, 0};  // digit low-bit positions
  constexpr int SBITS[4] = {45, 33, 22, 11}; // resolved-prefix shift

#pragma unroll
  for (int p = 0; p < 4; ++p) {
    if (!done) {  // block-uniform (all threads derive done identically)
      // zero histogram (4096 bins, 16/thread via b128 stores)
      const uint4 z4 = {0u, 0u, 0u, 0u};
#pragma unroll
      for (int i = 0; i < 4; ++i) *(uint4*)&s_hist[t * 16 + i * 4] = z4;
      __syncthreads();

      // accumulate: candidates are keys whose resolved prefix matches hi
#pragma unroll
      for (int j = 0; j < 32; ++j) {
        const u64 key = ((u64)D[j] << 13) | (u32)(t * 32 + j);
        if ((key >> SBITS[p]) == hi)
          atomicAdd(&s_hist[(u32)(key >> SHIFT[p]) & 4095u], 1u);
      }
      __syncthreads();

      // per-thread 16-bin group sum + block prefix (DPP scan + wave hop)
      const uint4 h0 = *(const uint4*)&s_hist[t * 16 + 0];
      const uint4 h1 = *(const uint4*)&s_hist[t * 16 + 4];
      const uint4 h2 = *(const uint4*)&s_hist[t * 16 + 8];
      const uint4 h3 = *(const uint4*)&s_hist[t * 16 + 12];
      const u32 ls = h0.x + h0.y + h0.z + h0.w + h1.x + h1.y + h1.z + h1.w +
                     h2.x + h2.y + h2.z + h2.w + h3.x + h3.y + h3.z + h3.w;
      const u32 incl = wave_scan_incl(ls);
      if ((t & 63) == 63) s_wsum[w] = incl;
      __syncthreads();
      u32 base = 0;
      if (w > 0) base += s_wsum[0];
      if (w > 1) base += s_wsum[1];
      if (w > 2) base += s_wsum[2];
      const u32 pre_grp = base + incl - ls;  // exclusive prefix of my group

      // unique crossing thread locates the k_rem-crossing bin in its group
      if (pre_grp < k_rem && k_rem <= pre_grp + ls) {
        const u32 hh[16] = {h0.x, h0.y, h0.z, h0.w, h1.x, h1.y, h1.z, h1.w,
                            h2.x, h2.y, h2.z, h2.w, h3.x, h3.y, h3.z, h3.w};
        u32 c = pre_grp;
#pragma unroll
        for (int i = 0; i < 16; ++i) {
          const u32 h = hh[i];
          if (k_rem > c && k_rem <= c + h) {
            s_bin = (u32)(t * 16 + i);
            s_r = k_rem - c;
            s_full = (k_rem - c == h) ? 1u : 0u;
          }
          c += h;
        }
      }
      __syncthreads();

      const u32 bin = s_bin;
      const u32 r = s_r;
      const u32 fullf = s_full;
      hi = (hi << (SBITS[p] - SHIFT[p])) | bin;
      if (fullf) {  // whole bin included: THR = largest key with this prefix
        thr = (SHIFT[p] > 0)
                  ? ((hi << SHIFT[p]) | ((1ULL << SHIFT[p]) - 1ULL))
                  : hi;
        done = true;  // pass 3 always terminates here (keys unique, h==1)
      } else {
        k_rem = r;
      }
    }
  }

  // --- extraction: exactly 32 keys satisfy key <= thr ---
  if (t == 0) s_cnt = 0;
  __syncthreads();
#pragma unroll
  for (int j = 0; j < 32; ++j) {
    const u64 key = ((u64)D[j] << 13) | (u32)(t * 32 + j);
    if (key <= thr) {
      const u32 pos = atomicAdd(&s_cnt, 1u);
      s_nbr[pos] = t * 32 + j;
    }
  }
  __syncthreads();

  // --- feature mean: thread t -> channel t&127, half t>>7 sums 16 rows ---
  const int c = t & (CC - 1);
  const int half = t >> 7;
  const float* fb = feats + (size_t)b * NN * CC;
  float s = 0.0f;
#pragma unroll
  for (int k = 0; k < 16; ++k) {
    const int p = s_nbr[half * 16 + k];
    s = __fadd_rn(s, fb[(size_t)p * CC + c]);
  }
  if (half == 1) s_sum[c] = s;
  __syncthreads();
  if (half == 0) {
    const float tot = __fadd_rn(s, s_sum[c]);        // low16 + high16
    out_feats[(size_t)q * CC + c] = tot * 0.03125f;  // exact /32
  }
}

// ---------------------------------------------------------------------------
extern "C" void kernel_launch(void* const* d_in, const int* in_sizes, int n_in,
                              void* d_out, int out_size, void* d_ws, size_t ws_size,
                              hipStream_t stream) {
  const float* coords = (const float*)d_in[0];
  const float* feats  = (const float*)d_in[1];
  float* out_coords = (float*)d_out;                        // B*M*3
  float* out_feats  = (float*)d_out + (size_t)BB * MM * 3;  // B*M*C

  fps_kernel<<<BB, FPS_T, 0, stream>>>(coords, out_coords);
  knn_mean_kernel<<<BB * MM, 256, 0, stream>>>(coords, feats, out_coords,
                                               out_feats);
}